// Round 1
// baseline (221.200 us; speedup 1.0000x reference)
//
#include <hip/hip_runtime.h>
#include <hip/hip_bf16.h>

// AELoss (associative embedding): N=32 batches, M=30 persons, K=17 joints,
// tags [N, K*H*W, 1] fp32, joints [N, M, K, 2] int32 (idx, vis).
// Outputs: pushes[32] then pulls[32] concatenated in d_out (fp32).

#define AE_N 32
#define AE_M 30
#define AE_K 17
#define AE_KHW (17 * 256 * 256)

__global__ __launch_bounds__(64) void aeloss_kernel(
    const float* __restrict__ tags,
    const int* __restrict__ joints,
    float* __restrict__ out)
{
    const int n = blockIdx.x;
    const int tid = threadIdx.x;

    __shared__ float s_mu[AE_M];
    __shared__ float s_pull[AE_M];
    __shared__ float s_pv[AE_M];

    if (tid < AE_M) {
        // one thread per person: gather 17 tags, two-pass mean / MSD
        const int* jp = joints + (((long long)n * AE_M + tid) * AE_K) * 2;
        const float* tp = tags + (long long)n * AE_KHW;

        float t[AE_K];
        float v[AE_K];
        float sum_tv = 0.0f;
        float cnt = 0.0f;
#pragma unroll
        for (int k = 0; k < AE_K; ++k) {
            int idx = jp[2 * k];
            int vis = jp[2 * k + 1];
            float tv = tp[idx];
            float vv = (vis > 0) ? 1.0f : 0.0f;
            t[k] = tv;
            v[k] = vv;
            sum_tv += tv * vv;
            cnt += vv;
        }
        float cnt_s = fmaxf(cnt, 1.0f);
        float mu = sum_tv / cnt_s;
        float pp = 0.0f;
#pragma unroll
        for (int k = 0; k < AE_K; ++k) {
            float d = t[k] - mu;
            pp += v[k] * d * d;
        }
        pp /= cnt_s;
        bool valid = (cnt > 0.0f);
        s_mu[tid] = mu;
        s_pull[tid] = valid ? pp : 0.0f;
        s_pv[tid] = valid ? 1.0f : 0.0f;
    }
    __syncthreads();

    if (tid == 0) {
        float pull = 0.0f, nt = 0.0f;
        for (int m = 0; m < AE_M; ++m) {
            pull += s_pull[m];
            nt += s_pv[m];
        }
        float push = 0.0f;
        for (int i = 0; i < AE_M; ++i) {
            if (s_pv[i] > 0.0f) {
                float mi = s_mu[i];
                for (int j = 0; j < AE_M; ++j) {
                    if (s_pv[j] > 0.0f) {
                        float d = mi - s_mu[j];
                        push += expf(-(d * d));
                    }
                }
            }
        }
        push -= nt;
        float denom = fmaxf((nt - 1.0f) * nt, 1.0f);
        out[n] = push / denom * 0.5f;                 // push loss
        out[AE_N + n] = pull / fmaxf(nt, 1.0f);       // pull loss
    }
}

extern "C" void kernel_launch(void* const* d_in, const int* in_sizes, int n_in,
                              void* d_out, int out_size, void* d_ws, size_t ws_size,
                              hipStream_t stream) {
    const float* tags = (const float*)d_in[0];
    const int* joints = (const int*)d_in[1];
    float* out = (float*)d_out;
    aeloss_kernel<<<AE_N, 64, 0, stream>>>(tags, joints, out);
}

// Round 2
// 168.510 us; speedup vs baseline: 1.3127x; 1.3127x over previous
//
#include <hip/hip_runtime.h>
#include <hip/hip_bf16.h>

// AELoss (associative embedding): N=32 batches, M=30 persons, K=17 joints,
// tags [N, K*H*W, 1] fp32, joints [N, M, K, 2] int32 (idx, vis).
// Outputs: pushes[32] then pulls[32] concatenated in d_out (fp32).
//
// One block per batch, 64 threads (1 wave). Phase 1: lanes 0..29 each own one
// person (17 gathers, mean, MSD). Phase 2: all 64 lanes split the 30x30=900
// pairwise push terms (~15/lane), then a single 64-wide butterfly reduces
// (push, pull, n) together. Serial tid==0 tail (was ~900 expf iters) removed.

#define AE_N 32
#define AE_M 30
#define AE_K 17
#define AE_KHW (17 * 256 * 256)

__global__ __launch_bounds__(64) void aeloss_kernel(
    const float* __restrict__ tags,
    const int* __restrict__ joints,
    float* __restrict__ out)
{
    const int n = blockIdx.x;
    const int tid = threadIdx.x;

    __shared__ float s_mu[AE_M];
    __shared__ float s_pv[AE_M];

    float pull_part = 0.0f;
    float nt_part = 0.0f;

    if (tid < AE_M) {
        const int* jp = joints + (((long long)n * AE_M + tid) * AE_K) * 2;
        const float* tp = tags + (long long)n * AE_KHW;

        float t[AE_K];
        float v[AE_K];
        float sum_tv = 0.0f;
        float cnt = 0.0f;
#pragma unroll
        for (int k = 0; k < AE_K; ++k) {
            int idx = jp[2 * k];
            int vis = jp[2 * k + 1];
            float tv = tp[idx];
            float vv = (vis > 0) ? 1.0f : 0.0f;
            t[k] = tv;
            v[k] = vv;
            sum_tv += tv * vv;
            cnt += vv;
        }
        float cnt_s = fmaxf(cnt, 1.0f);
        float mu = sum_tv / cnt_s;
        float pp = 0.0f;
#pragma unroll
        for (int k = 0; k < AE_K; ++k) {
            float d = t[k] - mu;
            pp += v[k] * d * d;
        }
        pp /= cnt_s;
        float valid = (cnt > 0.0f) ? 1.0f : 0.0f;
        s_mu[tid] = mu;            // mu == 0 when no valid joints (sum_tv==0, cnt_s==1)
        s_pv[tid] = valid;
        pull_part = valid * pp;
        nt_part = valid;
    }
    __syncthreads();

    // 900 pairwise push terms split across 64 lanes (masked multiply, no branch)
    float push_part = 0.0f;
    for (int p = tid; p < AE_M * AE_M; p += 64) {
        int i = p / AE_M;           // constant div -> magic multiply
        int j = p - i * AE_M;
        float d = s_mu[i] - s_mu[j];
        push_part += s_pv[i] * s_pv[j] * __expf(-(d * d));
    }

    // butterfly-reduce (push, pull, n) across the full wave
#pragma unroll
    for (int off = 32; off >= 1; off >>= 1) {
        push_part += __shfl_xor(push_part, off);
        pull_part += __shfl_xor(pull_part, off);
        nt_part   += __shfl_xor(nt_part, off);
    }

    if (tid == 0) {
        float nt = nt_part;
        float push = push_part - nt;   // subtract diagonal, as in reference
        float denom = fmaxf((nt - 1.0f) * nt, 1.0f);
        out[n] = push / denom * 0.5f;                 // push loss
        out[AE_N + n] = pull_part / fmaxf(nt, 1.0f);  // pull loss
    }
}

extern "C" void kernel_launch(void* const* d_in, const int* in_sizes, int n_in,
                              void* d_out, int out_size, void* d_ws, size_t ws_size,
                              hipStream_t stream) {
    const float* tags = (const float*)d_in[0];
    const int* joints = (const int*)d_in[1];
    float* out = (float*)d_out;
    aeloss_kernel<<<AE_N, 64, 0, stream>>>(tags, joints, out);
}